// Round 3
// baseline (9768.243 us; speedup 1.0000x reference)
//
#include <hip/hip_runtime.h>

typedef unsigned short ushort_t;

__device__ __forceinline__ float bf2f(ushort_t u) {
    return __uint_as_float(((unsigned)u) << 16);
}
__device__ __forceinline__ ushort_t f2bf(float f) {
    unsigned u = __float_as_uint(f);
    unsigned r = u + 0x7FFFu + ((u >> 16) & 1u);
    return (ushort_t)(r >> 16);
}
// Load input element i from a harness buffer: bf16 if f32==0, fp32 if f32!=0.
__device__ __forceinline__ float ldin(const ushort_t* p, size_t i, int f32) {
    return f32 ? ((const float*)p)[i] : bf2f(p[i]);
}

// dtype probe: Wq ~ N(0,1/1024) -> as bf16 every |v| <= ~0.2. fp32 data read as
// ushort halves has random exponents -> |v|>1 or NaN with prob ~1/2 per pair.
__global__ __launch_bounds__(256) void probe_kernel(const ushort_t* __restrict__ W,
                                                    int* __restrict__ flag) {
    __shared__ int bad;
    if (threadIdx.x == 0) bad = 0;
    __syncthreads();
    int local = 0;
    for (int i = threadIdx.x; i < 32768; i += 256) {
        float v = bf2f(W[i]);
        if (!(fabsf(v) <= 1.0f)) local = 1;   // catches NaN too
    }
    if (local) atomicOr(&bad, 1);
    __syncthreads();
    if (threadIdx.x == 0) flag[0] = bad ? 1 : 0;
}

// C[m][j] = scale * sum_k A[m][k]*B[k][j], fp32 accum.
// aMode/bMode: 0 = operand always bf16 (workspace), 1 = dtype per flag.
// cF32: 1 = store fp32 (harness output), 0 = store bf16 (workspace).
__global__ __launch_bounds__(256) void gemm_kernel(
    const ushort_t* __restrict__ A, const ushort_t* __restrict__ B,
    void* __restrict__ C, int M, int K, int N, float scale,
    const int* __restrict__ flagp, int aMode, int bMode, int cF32)
{
    __shared__ float As[16][64];
    __shared__ float Bs[16][64];
    const int f32 = flagp[0];
    const int aF = aMode ? f32 : 0;
    const int bF = bMode ? f32 : 0;
    const int t  = threadIdx.x;
    const int tx = t & 15;
    const int ty = t >> 4;
    const int m0 = blockIdx.y * 64;
    const int n0 = blockIdx.x * 64;

    float acc[4][4];
#pragma unroll
    for (int i = 0; i < 4; ++i)
#pragma unroll
        for (int j = 0; j < 4; ++j) acc[i][j] = 0.f;

    for (int k0 = 0; k0 < K; k0 += 16) {
        for (int i = t; i < 64 * 16; i += 256) {
            int row = i >> 4, col = i & 15;
            As[col][row] = ldin(A, (size_t)(m0 + row) * K + k0 + col, aF);
        }
        for (int i = t; i < 16 * 64; i += 256) {
            int row = i >> 6, col = i & 63;
            Bs[row][col] = ldin(B, (size_t)(k0 + row) * N + n0 + col, bF);
        }
        __syncthreads();
#pragma unroll
        for (int kk = 0; kk < 16; ++kk) {
            float a[4], b[4];
#pragma unroll
            for (int i = 0; i < 4; ++i) a[i] = As[kk][ty * 4 + i];
#pragma unroll
            for (int j = 0; j < 4; ++j) b[j] = Bs[kk][tx * 4 + j];
#pragma unroll
            for (int i = 0; i < 4; ++i)
#pragma unroll
                for (int j = 0; j < 4; ++j) acc[i][j] += a[i] * b[j];
        }
        __syncthreads();
    }
#pragma unroll
    for (int i = 0; i < 4; ++i)
#pragma unroll
        for (int j = 0; j < 4; ++j) {
            size_t idx = (size_t)(m0 + ty * 4 + i) * N + n0 + tx * 4 + j;
            float v = acc[i][j] * scale;
            if (cF32) ((float*)C)[idx] = v;
            else      ((ushort_t*)C)[idx] = f2bf(v);
        }
}

// Attention. Q,K,V,O workspace: bf16, layout [N,T,H,S]. Mask: dtype per flag, [N,H,T,T].
#define T_SEQ 2048
#define QT 4

__global__ __launch_bounds__(256) void attn_kernel(
    const ushort_t* __restrict__ Q, const ushort_t* __restrict__ K,
    const ushort_t* __restrict__ V, const ushort_t* __restrict__ Mask,
    ushort_t* __restrict__ O, const int* __restrict__ flagp)
{
    __shared__ float sQ[QT][64];
    __shared__ float sS[QT][T_SEQ];
    __shared__ float pv[4][QT][64];
    __shared__ float red[256];
    __shared__ float rcp_s[QT];

    const int f32 = flagp[0];
    const int t  = threadIdx.x;
    const int q0 = blockIdx.x * QT;
    const int h  = blockIdx.y;
    const int n  = blockIdx.z;

    for (int i = t; i < QT * 64; i += 256) {
        int qi = i >> 6, s = i & 63;
        sQ[qi][s] = bf2f(Q[((size_t)(n * T_SEQ + q0 + qi) << 10) + h * 64 + s]);
    }
    __syncthreads();

    // phase 1: scores = Q.K^T + mask*NEG_INF
    for (int j = 0; j < T_SEQ / 256; ++j) {
        const int r = j * 256 + t;
        const uint4* krow = (const uint4*)(K + ((size_t)(n * T_SEQ + r) << 10) + h * 64);
        float dot[QT];
#pragma unroll
        for (int qi = 0; qi < QT; ++qi) dot[qi] = 0.f;
#pragma unroll
        for (int c = 0; c < 8; ++c) {
            uint4 w = krow[c];
            float kv[8];
            kv[0] = __uint_as_float(w.x << 16); kv[1] = __uint_as_float(w.x & 0xFFFF0000u);
            kv[2] = __uint_as_float(w.y << 16); kv[3] = __uint_as_float(w.y & 0xFFFF0000u);
            kv[4] = __uint_as_float(w.z << 16); kv[5] = __uint_as_float(w.z & 0xFFFF0000u);
            kv[6] = __uint_as_float(w.w << 16); kv[7] = __uint_as_float(w.w & 0xFFFF0000u);
#pragma unroll
            for (int qi = 0; qi < QT; ++qi) {
                float d = 0.f;
#pragma unroll
                for (int s2 = 0; s2 < 8; ++s2) d += kv[s2] * sQ[qi][c * 8 + s2];
                dot[qi] += d;
            }
        }
#pragma unroll
        for (int qi = 0; qi < QT; ++qi) {
            float mv = ldin(Mask, (((size_t)(n * 16 + h) * T_SEQ) + (q0 + qi)) * T_SEQ + r, f32);
            sS[qi][r] = dot[qi] - 1e9f * mv;
        }
    }
    __syncthreads();

    // phase 2: softmax (fp32, two-pass)
    for (int qi = 0; qi < QT; ++qi) {
        float lm = -3e38f;
        for (int r = t; r < T_SEQ; r += 256) lm = fmaxf(lm, sS[qi][r]);
        red[t] = lm; __syncthreads();
        for (int w = 128; w > 0; w >>= 1) {
            if (t < w) red[t] = fmaxf(red[t], red[t + w]);
            __syncthreads();
        }
        const float mx = red[0];
        __syncthreads();
        float ls = 0.f;
        for (int r = t; r < T_SEQ; r += 256) {
            float e = __expf(sS[qi][r] - mx);
            sS[qi][r] = e;
            ls += e;
        }
        red[t] = ls; __syncthreads();
        for (int w = 128; w > 0; w >>= 1) {
            if (t < w) red[t] += red[t + w];
            __syncthreads();
        }
        if (t == 0) rcp_s[qi] = 1.0f / red[0];
        __syncthreads();
    }

    // phase 3: O = P.V
    const int s  = t & 63;
    const int rc = t >> 6;
    float acc[QT];
#pragma unroll
    for (int qi = 0; qi < QT; ++qi) acc[qi] = 0.f;
    for (int r = rc; r < T_SEQ; r += 4) {
        float v = bf2f(V[((size_t)(n * T_SEQ + r) << 10) + h * 64 + s]);
#pragma unroll
        for (int qi = 0; qi < QT; ++qi) acc[qi] += sS[qi][r] * v;
    }
#pragma unroll
    for (int qi = 0; qi < QT; ++qi) pv[rc][qi][s] = acc[qi];
    __syncthreads();
    {
        const int qi = rc;
        float o = (pv[0][qi][s] + pv[1][qi][s] + pv[2][qi][s] + pv[3][qi][s]) * rcp_s[qi];
        O[((size_t)(n * T_SEQ + q0 + qi) << 10) + h * 64 + s] = f2bf(o);
    }
}

extern "C" void kernel_launch(void* const* d_in, const int* in_sizes, int n_in,
                              void* d_out, int out_size, void* d_ws, size_t ws_size,
                              hipStream_t stream) {
    const ushort_t* q_seqs = (const ushort_t*)d_in[0];
    const ushort_t* r_seqs = (const ushort_t*)d_in[1];
    const ushort_t* mask   = (const ushort_t*)d_in[2];
    const ushort_t* Wq     = (const ushort_t*)d_in[3];
    const ushort_t* Wk     = (const ushort_t*)d_in[4];
    const ushort_t* Wv     = (const ushort_t*)d_in[5];
    const ushort_t* Wo     = (const ushort_t*)d_in[6];

    int* flag = (int*)d_ws;                                   // 4 KiB reserved
    ushort_t* wsQ = (ushort_t*)((char*)d_ws + 4096);          // 8 MiB each, bf16
    ushort_t* wsK = wsQ + 4194304;
    ushort_t* wsV = wsK + 4194304;
    ushort_t* wsO = wsV + 4194304;

    const int M = 4096, Kd = 1024, Nd = 1024;
    dim3 gblock(256);
    dim3 ggrid(Nd / 64, M / 64);

    hipLaunchKernelGGL(probe_kernel, dim3(1), gblock, 0, stream, Wq, flag);

    hipLaunchKernelGGL(gemm_kernel, ggrid, gblock, 0, stream, q_seqs, Wq, (void*)wsQ, M, Kd, Nd, 0.125f, flag, 1, 1, 0);
    hipLaunchKernelGGL(gemm_kernel, ggrid, gblock, 0, stream, r_seqs, Wk, (void*)wsK, M, Kd, Nd, 1.0f,   flag, 1, 1, 0);
    hipLaunchKernelGGL(gemm_kernel, ggrid, gblock, 0, stream, r_seqs, Wv, (void*)wsV, M, Kd, Nd, 1.0f,   flag, 1, 1, 0);

    dim3 agrid(T_SEQ / QT, 16, 2);
    hipLaunchKernelGGL(attn_kernel, agrid, gblock, 0, stream, wsQ, wsK, wsV, mask, wsO, flag);

    // output projection -> fp32 d_out
    hipLaunchKernelGGL(gemm_kernel, ggrid, gblock, 0, stream, wsO, Wo, d_out, M, Kd, Nd, 1.0f, flag, 0, 1, 1);
}

// Round 4
// 989.404 us; speedup vs baseline: 9.8729x; 9.8729x over previous
//
#include <hip/hip_runtime.h>

typedef unsigned short ushort_t;
typedef __attribute__((ext_vector_type(8))) short bf16x8;   // 8 bf16 in 4 VGPRs
typedef __attribute__((ext_vector_type(4))) float f32x4;

#define T_SEQ 2048

__device__ __forceinline__ ushort_t f2bf(float f) {
    unsigned u = __float_as_uint(f);
    unsigned r = u + 0x7FFFu + ((u >> 16) & 1u);
    return (ushort_t)(r >> 16);
}
__device__ __forceinline__ unsigned pack2(float a, float b) {
    return (unsigned)f2bf(a) | ((unsigned)f2bf(b) << 16);
}

// C[M,N] = scale * A[M,K] * B[K,N]; A fp32-or-bf16 (aF32), B fp32, C fp32-or-bf16 (cF32).
// Tile 64x64, 4 waves, K-step 32. MFMA 16x16x32 bf16, fp32 accum.
__global__ __launch_bounds__(256) void gemm_mfma(
    const void* __restrict__ Av, const float* __restrict__ B,
    void* __restrict__ Cv, int M, int K, int N, float scale,
    int aF32, int cF32)
{
    __shared__ ushort_t As[64][40];   // [m][k], +8 pad (row=80B, 16B-aligned)
    __shared__ ushort_t Bs[64][40];   // [n][k] (transposed), +8 pad
    const int t = threadIdx.x;
    const int lane = t & 63, wave = t >> 6;
    const int col = lane & 15, quad = lane >> 4;
    const int m0 = blockIdx.y * 64, n0 = blockIdx.x * 64;

    f32x4 acc[4];
#pragma unroll
    for (int i = 0; i < 4; ++i) acc[i] = (f32x4){0.f, 0.f, 0.f, 0.f};

    const int am = t >> 2, ak = (t & 3) * 8;   // A staging: 4 thr/row x 8 elems
    const int bk = t >> 3, bn = (t & 7) * 8;   // B staging: 8 thr/row x 8 elems

    for (int k0 = 0; k0 < K; k0 += 32) {
        // ---- stage A tile (64 x 32) as bf16, k-contiguous ----
        if (aF32) {
            const float* Ap = (const float*)Av + (size_t)(m0 + am) * K + k0 + ak;
            float4 f0 = *(const float4*)Ap;
            float4 f1 = *(const float4*)(Ap + 4);
            uint4 w;
            w.x = pack2(f0.x, f0.y); w.y = pack2(f0.z, f0.w);
            w.z = pack2(f1.x, f1.y); w.w = pack2(f1.z, f1.w);
            *(uint4*)&As[am][ak] = w;
        } else {
            const ushort_t* Ap = (const ushort_t*)Av + (size_t)(m0 + am) * K + k0 + ak;
            *(uint4*)&As[am][ak] = *(const uint4*)Ap;
        }
        // ---- stage B tile (32 x 64) transposed -> Bs[n][k] ----
        {
            const float* Bp = B + (size_t)(k0 + bk) * N + n0 + bn;
            float4 f0 = *(const float4*)Bp;
            float4 f1 = *(const float4*)(Bp + 4);
            Bs[bn + 0][bk] = f2bf(f0.x); Bs[bn + 1][bk] = f2bf(f0.y);
            Bs[bn + 2][bk] = f2bf(f0.z); Bs[bn + 3][bk] = f2bf(f0.w);
            Bs[bn + 4][bk] = f2bf(f1.x); Bs[bn + 5][bk] = f2bf(f1.y);
            Bs[bn + 6][bk] = f2bf(f1.z); Bs[bn + 7][bk] = f2bf(f1.w);
        }
        __syncthreads();
        // A-frag: m = lane&15 (wave strip), k = quad*8 + j  (K=32 per MFMA)
        bf16x8 a = *(const bf16x8*)&As[wave * 16 + col][quad * 8];
#pragma unroll
        for (int nt = 0; nt < 4; ++nt) {
            bf16x8 b = *(const bf16x8*)&Bs[nt * 16 + col][quad * 8];
            acc[nt] = __builtin_amdgcn_mfma_f32_16x16x32_bf16(a, b, acc[nt], 0, 0, 0);
        }
        __syncthreads();
    }
    // epilogue: C/D layout row = quad*4 + reg, col = lane&15
#pragma unroll
    for (int nt = 0; nt < 4; ++nt)
#pragma unroll
        for (int r = 0; r < 4; ++r) {
            int row = m0 + wave * 16 + quad * 4 + r;
            int cc  = n0 + nt * 16 + col;
            float v = acc[nt][r] * scale;
            if (cF32) ((float*)Cv)[(size_t)row * N + cc] = v;
            else      ((ushort_t*)Cv)[(size_t)row * N + cc] = f2bf(v);
        }
}

// Flash attention. Q,K,V,O: bf16 ws, [N,T,H,S]. Mask: fp32 [N,H,T,T].
// Block = (n, h, 64 q-rows); iterate 64-row K/V tiles with online softmax.
__global__ __launch_bounds__(256) void attn_mfma(
    const ushort_t* __restrict__ Q, const ushort_t* __restrict__ K,
    const ushort_t* __restrict__ V, const float* __restrict__ Mask,
    ushort_t* __restrict__ O)
{
    __shared__ ushort_t Qs[64][72];   // [q][s]
    __shared__ ushort_t Ks[64][72];   // [kv][s]
    __shared__ ushort_t Vs[64][72];   // [s][kv]  (transposed)
    __shared__ ushort_t Ps[64][72];   // [q][kv]

    const int t = threadIdx.x;
    const int lane = t & 63, wave = t >> 6;
    const int col = lane & 15, quad = lane >> 4;
    const int q0 = blockIdx.x * 64;
    const int h = blockIdx.y, n = blockIdx.z;

    // stage Q once: 4 thr/row, 2 x uint4 (16 bf16) each
    {
        const int r = t >> 2, cc = (t & 3) * 16;
        const ushort_t* Qp = Q + ((size_t)(n * T_SEQ + q0 + r) << 10) + h * 64 + cc;
        *(uint4*)&Qs[r][cc]     = *(const uint4*)Qp;
        *(uint4*)&Qs[r][cc + 8] = *(const uint4*)(Qp + 8);
    }

    f32x4 o_acc[4];
#pragma unroll
    for (int i = 0; i < 4; ++i) o_acc[i] = (f32x4){0.f, 0.f, 0.f, 0.f};
    float m_run[4], l_run[4];
#pragma unroll
    for (int r = 0; r < 4; ++r) { m_run[r] = -3e38f; l_run[r] = 0.f; }

    // mask row base for this lane's 4 output rows (C/D layout rows)
    const float* Mrow = Mask + ((size_t)(n * 16 + h) * T_SEQ + (q0 + wave * 16 + quad * 4)) * T_SEQ;

    for (int kt = 0; kt < T_SEQ / 64; ++kt) {
        const int kv0 = kt * 64;
        // stage K tile [kv][s]
        {
            const int r = t >> 2, cc = (t & 3) * 16;
            const ushort_t* Kp = K + ((size_t)(n * T_SEQ + kv0 + r) << 10) + h * 64 + cc;
            *(uint4*)&Ks[r][cc]     = *(const uint4*)Kp;
            *(uint4*)&Ks[r][cc + 8] = *(const uint4*)(Kp + 8);
        }
        // stage V tile transposed -> Vs[s][kv]
        {
            const int kv = t >> 2, cc = (t & 3) * 16;
            const ushort_t* Vp = V + ((size_t)(n * T_SEQ + kv0 + kv) << 10) + h * 64 + cc;
            uint4 w0 = *(const uint4*)Vp;
            uint4 w1 = *(const uint4*)(Vp + 8);
            Vs[cc + 0][kv] = (ushort_t)(w0.x); Vs[cc + 1][kv] = (ushort_t)(w0.x >> 16);
            Vs[cc + 2][kv] = (ushort_t)(w0.y); Vs[cc + 3][kv] = (ushort_t)(w0.y >> 16);
            Vs[cc + 4][kv] = (ushort_t)(w0.z); Vs[cc + 5][kv] = (ushort_t)(w0.z >> 16);
            Vs[cc + 6][kv] = (ushort_t)(w0.w); Vs[cc + 7][kv] = (ushort_t)(w0.w >> 16);
            Vs[cc + 8][kv] = (ushort_t)(w1.x); Vs[cc + 9][kv] = (ushort_t)(w1.x >> 16);
            Vs[cc +10][kv] = (ushort_t)(w1.y); Vs[cc +11][kv] = (ushort_t)(w1.y >> 16);
            Vs[cc +12][kv] = (ushort_t)(w1.z); Vs[cc +13][kv] = (ushort_t)(w1.z >> 16);
            Vs[cc +14][kv] = (ushort_t)(w1.w); Vs[cc +15][kv] = (ushort_t)(w1.w >> 16);
        }
        __syncthreads();

        // ---- S = Q . K^T  (64x64 per block; wave strip = 16 q-rows) ----
        bf16x8 qa0 = *(const bf16x8*)&Qs[wave * 16 + col][quad * 8];
        bf16x8 qa1 = *(const bf16x8*)&Qs[wave * 16 + col][32 + quad * 8];
        f32x4 s_acc[4];
#pragma unroll
        for (int nt = 0; nt < 4; ++nt) {
            bf16x8 kb0 = *(const bf16x8*)&Ks[nt * 16 + col][quad * 8];
            bf16x8 kb1 = *(const bf16x8*)&Ks[nt * 16 + col][32 + quad * 8];
            f32x4 z = (f32x4){0.f, 0.f, 0.f, 0.f};
            z = __builtin_amdgcn_mfma_f32_16x16x32_bf16(qa0, kb0, z, 0, 0, 0);
            z = __builtin_amdgcn_mfma_f32_16x16x32_bf16(qa1, kb1, z, 0, 0, 0);
            s_acc[nt] = z;
        }
        // ---- + mask * NEG_INF (coalesced: 16 lanes read 16 contiguous floats) ----
#pragma unroll
        for (int nt = 0; nt < 4; ++nt)
#pragma unroll
            for (int r = 0; r < 4; ++r)
                s_acc[nt][r] -= 1e9f * Mrow[(size_t)r * T_SEQ + kv0 + nt * 16 + col];

        // ---- online softmax (per C/D row; reduce across 16 lanes of the quad) ----
#pragma unroll
        for (int r = 0; r < 4; ++r) {
            float mx = fmaxf(fmaxf(s_acc[0][r], s_acc[1][r]), fmaxf(s_acc[2][r], s_acc[3][r]));
#pragma unroll
            for (int off = 1; off < 16; off <<= 1) mx = fmaxf(mx, __shfl_xor(mx, off));
            float mnew = fmaxf(m_run[r], mx);
            float alpha = __expf(m_run[r] - mnew);
            m_run[r] = mnew;
            float rs = 0.f;
#pragma unroll
            for (int nt = 0; nt < 4; ++nt) {
                float p = __expf(s_acc[nt][r] - mnew);
                rs += p;
                Ps[wave * 16 + quad * 4 + r][nt * 16 + col] = f2bf(p);
            }
#pragma unroll
            for (int off = 1; off < 16; off <<= 1) rs += __shfl_xor(rs, off);
            l_run[r] = l_run[r] * alpha + rs;
#pragma unroll
            for (int st = 0; st < 4; ++st) o_acc[st][r] *= alpha;
        }
        __syncthreads();

        // ---- O += P . V ----
        bf16x8 pa0 = *(const bf16x8*)&Ps[wave * 16 + col][quad * 8];
        bf16x8 pa1 = *(const bf16x8*)&Ps[wave * 16 + col][32 + quad * 8];
#pragma unroll
        for (int st = 0; st < 4; ++st) {
            bf16x8 vb0 = *(const bf16x8*)&Vs[st * 16 + col][quad * 8];
            bf16x8 vb1 = *(const bf16x8*)&Vs[st * 16 + col][32 + quad * 8];
            o_acc[st] = __builtin_amdgcn_mfma_f32_16x16x32_bf16(pa0, vb0, o_acc[st], 0, 0, 0);
            o_acc[st] = __builtin_amdgcn_mfma_f32_16x16x32_bf16(pa1, vb1, o_acc[st], 0, 0, 0);
        }
        __syncthreads();
    }

    // ---- epilogue: normalize and store bf16 ----
#pragma unroll
    for (int r = 0; r < 4; ++r) {
        float inv = 1.0f / l_run[r];
        int qrow = q0 + wave * 16 + quad * 4 + r;
        size_t base = ((size_t)(n * T_SEQ + qrow) << 10) + h * 64;
#pragma unroll
        for (int st = 0; st < 4; ++st)
            O[base + st * 16 + col] = f2bf(o_acc[st][r] * inv);
    }
}

extern "C" void kernel_launch(void* const* d_in, const int* in_sizes, int n_in,
                              void* d_out, int out_size, void* d_ws, size_t ws_size,
                              hipStream_t stream) {
    const float* q_seqs = (const float*)d_in[0];   // [2,2048,1024] fp32
    const float* r_seqs = (const float*)d_in[1];   // [2,2048,1024] fp32
    const float* mask   = (const float*)d_in[2];   // [2,16,2048,2048] fp32
    const float* Wq     = (const float*)d_in[3];   // [1024,1024] fp32
    const float* Wk     = (const float*)d_in[4];
    const float* Wv     = (const float*)d_in[5];
    const float* Wo     = (const float*)d_in[6];

    ushort_t* wsQ = (ushort_t*)d_ws;               // bf16 [N,T,H,S] = 4096x1024
    ushort_t* wsK = wsQ + 4194304;
    ushort_t* wsV = wsK + 4194304;
    ushort_t* wsO = wsV + 4194304;

    const int M = 4096, Kd = 1024, Nd = 1024;
    dim3 blk(256);
    dim3 ggrid(Nd / 64, M / 64);

    // projections (Q scaled by S^-0.5 = 0.125)
    hipLaunchKernelGGL(gemm_mfma, ggrid, blk, 0, stream, (const void*)q_seqs, Wq, (void*)wsQ, M, Kd, Nd, 0.125f, 1, 0);
    hipLaunchKernelGGL(gemm_mfma, ggrid, blk, 0, stream, (const void*)r_seqs, Wk, (void*)wsK, M, Kd, Nd, 1.0f,   1, 0);
    hipLaunchKernelGGL(gemm_mfma, ggrid, blk, 0, stream, (const void*)r_seqs, Wv, (void*)wsV, M, Kd, Nd, 1.0f,   1, 0);

    // flash attention
    dim3 agrid(T_SEQ / 64, 16, 2);
    hipLaunchKernelGGL(attn_mfma, agrid, blk, 0, stream, wsQ, wsK, wsV, mask, wsO);

    // output projection -> fp32 d_out
    hipLaunchKernelGGL(gemm_mfma, ggrid, blk, 0, stream, (const void*)wsO, Wo, d_out, M, Kd, Nd, 1.0f, 0, 1);
}

// Round 5
// 986.417 us; speedup vs baseline: 9.9028x; 1.0030x over previous
//
#include <hip/hip_runtime.h>

typedef unsigned short ushort_t;
typedef __attribute__((ext_vector_type(8))) short bf16x8;   // 8 bf16 = 4 VGPRs
typedef __attribute__((ext_vector_type(4))) float f32x4;

#define T_SEQ 2048

__device__ __forceinline__ ushort_t f2bf(float f) {
    unsigned u = __float_as_uint(f);
    unsigned r = u + 0x7FFFu + ((u >> 16) & 1u);
    return (ushort_t)(r >> 16);
}
__device__ __forceinline__ unsigned pack2(float a, float b) {
    return (unsigned)f2bf(a) | ((unsigned)f2bf(b) << 16);
}

typedef __attribute__((address_space(1))) void g_void;
typedef __attribute__((address_space(3))) void l_void;
// async global->LDS, 16B per lane; LDS dest = wave-uniform base + lane*16.
__device__ __forceinline__ void async16(const void* g, void* l) {
    __builtin_amdgcn_global_load_lds((g_void*)g, (l_void*)l, 16, 0, 0);
}

// ---- fp32 -> bf16, same layout. n/8 threads. ----
__global__ __launch_bounds__(256) void cvt_bf16(const float* __restrict__ in,
                                                ushort_t* __restrict__ out) {
    size_t i = ((size_t)blockIdx.x * 256 + threadIdx.x) * 8;
    float4 f0 = *(const float4*)(in + i);
    float4 f1 = *(const float4*)(in + i + 4);
    uint4 w;
    w.x = pack2(f0.x, f0.y); w.y = pack2(f0.z, f0.w);
    w.z = pack2(f1.x, f1.y); w.w = pack2(f1.z, f1.w);
    *(uint4*)(out + i) = w;
}

// ---- weight fp32 [1024][1024] ([k][n]) -> bf16 transposed out[n][k], row stride 1024 ----
__global__ __launch_bounds__(256) void cvt_w_t(const float* __restrict__ W,
                                               ushort_t* __restrict__ out) {
    __shared__ ushort_t Ls[64][72];
    const int t = threadIdx.x;
    const int k0 = blockIdx.y * 64, n0 = blockIdx.x * 64;
    {
        const int r = t >> 2, c = (t & 3) * 16;
        const float* p = W + (size_t)(k0 + r) * 1024 + n0 + c;
        float4 a = *(const float4*)p, b = *(const float4*)(p + 4);
        float4 c2 = *(const float4*)(p + 8), d = *(const float4*)(p + 12);
        uint4 w0, w1;
        w0.x = pack2(a.x, a.y); w0.y = pack2(a.z, a.w);
        w0.z = pack2(b.x, b.y); w0.w = pack2(b.z, b.w);
        w1.x = pack2(c2.x, c2.y); w1.y = pack2(c2.z, c2.w);
        w1.z = pack2(d.x, d.y); w1.w = pack2(d.z, d.w);
        *(uint4*)&Ls[r][c] = w0;
        *(uint4*)&Ls[r][c + 8] = w1;
    }
    __syncthreads();
    {
        const int nn = t >> 2, kc = (t & 3) * 16;
        unsigned u[8];
#pragma unroll
        for (int a2 = 0; a2 < 8; ++a2)
            u[a2] = (unsigned)Ls[kc + 2 * a2][nn] | ((unsigned)Ls[kc + 2 * a2 + 1][nn] << 16);
        uint4 w0 = {u[0], u[1], u[2], u[3]}, w1 = {u[4], u[5], u[6], u[7]};
        ushort_t* op = out + (size_t)(n0 + nn) * 1024 + k0 + kc;
        *(uint4*)op = w0;
        *(uint4*)(op + 8) = w1;
    }
}

// ---- V bf16 [b*2048+t][ldin] (col offset pre-applied) -> VT [((b*16+h)*64+s)][2048] ----
__global__ __launch_bounds__(256) void transpose_v(const ushort_t* __restrict__ Vin, int ldin,
                                                   ushort_t* __restrict__ VT) {
    __shared__ ushort_t Ls[64][72];
    const int t = threadIdx.x;
    const int t0 = blockIdx.x * 64;
    const int h = blockIdx.y, b = blockIdx.z;
    {
        const int r = t >> 2, c = (t & 3) * 16;
        const ushort_t* p = Vin + (size_t)(b * T_SEQ + t0 + r) * ldin + h * 64 + c;
        *(uint4*)&Ls[r][c] = *(const uint4*)p;
        *(uint4*)&Ls[r][c + 8] = *(const uint4*)(p + 8);
    }
    __syncthreads();
    {
        const int s = t >> 2, tc = (t & 3) * 16;
        unsigned u[8];
#pragma unroll
        for (int a2 = 0; a2 < 8; ++a2)
            u[a2] = (unsigned)Ls[tc + 2 * a2][s] | ((unsigned)Ls[tc + 2 * a2 + 1][s] << 16);
        uint4 w0 = {u[0], u[1], u[2], u[3]}, w1 = {u[4], u[5], u[6], u[7]};
        ushort_t* op = VT + ((size_t)(b * 16 + h) * 64 + s) * T_SEQ + t0 + tc;
        *(uint4*)op = w0;
        *(uint4*)(op + 8) = w1;
    }
}

// ---- m97-style GEMM: C[M,N] = scale * A[M,K] * Bt[N,K]^T, bf16 in, fp32 acc.
// 128x128 tile, BK=64, 4 waves (2x2 quadrants of 64x64), global_load_lds staging. ----
__global__ __launch_bounds__(256) void gemm_mfma128(
    const ushort_t* __restrict__ A, const ushort_t* __restrict__ Bt,
    void* __restrict__ Cv, int M, int N, int K, float scale, int cF32)
{
    __shared__ ushort_t As[128][64];
    __shared__ ushort_t Bs[128][64];
    const int t = threadIdx.x;
    const int lane = t & 63, wave = t >> 6;
    const int col = lane & 15, quad = lane >> 4;
    const int wm = wave & 1, wn = wave >> 1;
    const int m0 = blockIdx.y * 128, n0 = blockIdx.x * 128;

    f32x4 acc[4][4];
#pragma unroll
    for (int i = 0; i < 4; ++i)
#pragma unroll
        for (int j = 0; j < 4; ++j) acc[i][j] = (f32x4){0.f, 0.f, 0.f, 0.f};

    for (int k0 = 0; k0 < K; k0 += 64) {
#pragma unroll
        for (int j = 0; j < 4; ++j) {
            const int c = j * 256 + t;
            const int mr = c >> 3, kc = (c & 7) * 8;   // [row][16B-chunk]
            async16(A + (size_t)(m0 + mr) * K + k0 + kc,
                    (ushort_t*)As + (size_t)(j * 256 + wave * 64) * 8);
            async16(Bt + (size_t)(n0 + mr) * K + k0 + kc,
                    (ushort_t*)Bs + (size_t)(j * 256 + wave * 64) * 8);
        }
        __syncthreads();
#pragma unroll
        for (int kk = 0; kk < 2; ++kk) {
            bf16x8 a[4], b[4];
#pragma unroll
            for (int i = 0; i < 4; ++i)
                a[i] = *(const bf16x8*)&As[wm * 64 + i * 16 + col][kk * 32 + quad * 8];
#pragma unroll
            for (int j = 0; j < 4; ++j)
                b[j] = *(const bf16x8*)&Bs[wn * 64 + j * 16 + col][kk * 32 + quad * 8];
#pragma unroll
            for (int i = 0; i < 4; ++i)
#pragma unroll
                for (int j = 0; j < 4; ++j)
                    acc[i][j] = __builtin_amdgcn_mfma_f32_16x16x32_bf16(a[i], b[j], acc[i][j], 0, 0, 0);
        }
        __syncthreads();
    }
#pragma unroll
    for (int i = 0; i < 4; ++i) {
        const int row = m0 + wm * 64 + i * 16 + quad * 4;
#pragma unroll
        for (int j = 0; j < 4; ++j) {
            const int cc = n0 + wn * 64 + j * 16 + col;
#pragma unroll
            for (int r = 0; r < 4; ++r) {
                float v = acc[i][j][r] * scale;
                if (cF32) ((float*)Cv)[(size_t)(row + r) * N + cc] = v;
                else      ((ushort_t*)Cv)[(size_t)(row + r) * N + cc] = f2bf(v);
            }
        }
    }
}

// ---- flash attention: block = (64 q-rows, h, b). K rows strided ldk; V pre-transposed. ----
__global__ __launch_bounds__(256) void attn_mfma(
    const ushort_t* __restrict__ Q, int ldq,
    const ushort_t* __restrict__ K, int ldk,
    const ushort_t* __restrict__ VT,
    const float* __restrict__ Mask,
    ushort_t* __restrict__ O, int ldo)
{
    __shared__ ushort_t Qs[64][72];
    __shared__ ushort_t Ks[64][72];
    __shared__ ushort_t Vs[64][72];   // V^T tile: [s][kv]
    __shared__ ushort_t Ps[64][72];

    const int t = threadIdx.x;
    const int lane = t & 63, wave = t >> 6;
    const int col = lane & 15, quad = lane >> 4;
    const int q0 = blockIdx.x * 64;
    const int h = blockIdx.y, n = blockIdx.z;

    {   // stage Q once
        const int r = t >> 2, c = (t & 3) * 16;
        const ushort_t* p = Q + (size_t)(n * T_SEQ + q0 + r) * ldq + h * 64 + c;
        *(uint4*)&Qs[r][c]     = *(const uint4*)p;
        *(uint4*)&Qs[r][c + 8] = *(const uint4*)(p + 8);
    }
    __syncthreads();
    const bf16x8 qa0 = *(const bf16x8*)&Qs[wave * 16 + col][quad * 8];
    const bf16x8 qa1 = *(const bf16x8*)&Qs[wave * 16 + col][32 + quad * 8];

    f32x4 o_acc[4];
#pragma unroll
    for (int i = 0; i < 4; ++i) o_acc[i] = (f32x4){0.f, 0.f, 0.f, 0.f};
    float m_run[4], l_run[4];
#pragma unroll
    for (int r = 0; r < 4; ++r) { m_run[r] = -3e38f; l_run[r] = 0.f; }

    const float* Mrow = Mask + ((size_t)((n * 16 + h) * T_SEQ) + q0 + wave * 16 + quad * 4) * T_SEQ;

    for (int kt = 0; kt < T_SEQ / 64; ++kt) {
        const int kv0 = kt * 64;
        {   // stage K tile [kv][s]
            const int r = t >> 2, c = (t & 3) * 16;
            const ushort_t* p = K + (size_t)(n * T_SEQ + kv0 + r) * ldk + h * 64 + c;
            *(uint4*)&Ks[r][c]     = *(const uint4*)p;
            *(uint4*)&Ks[r][c + 8] = *(const uint4*)(p + 8);
        }
        {   // stage V^T tile [s][kv] (already transposed globally)
            const int s = t >> 2, tc = (t & 3) * 16;
            const ushort_t* p = VT + ((size_t)(n * 16 + h) * 64 + s) * T_SEQ + kv0 + tc;
            *(uint4*)&Vs[s][tc]     = *(const uint4*)p;
            *(uint4*)&Vs[s][tc + 8] = *(const uint4*)(p + 8);
        }
        __syncthreads();

        // S = Q . K^T
        f32x4 s_acc[4];
#pragma unroll
        for (int nt = 0; nt < 4; ++nt) {
            bf16x8 kb0 = *(const bf16x8*)&Ks[nt * 16 + col][quad * 8];
            bf16x8 kb1 = *(const bf16x8*)&Ks[nt * 16 + col][32 + quad * 8];
            f32x4 z = (f32x4){0.f, 0.f, 0.f, 0.f};
            z = __builtin_amdgcn_mfma_f32_16x16x32_bf16(qa0, kb0, z, 0, 0, 0);
            z = __builtin_amdgcn_mfma_f32_16x16x32_bf16(qa1, kb1, z, 0, 0, 0);
            s_acc[nt] = z;
        }
        // + mask * NEG_INF
#pragma unroll
        for (int nt = 0; nt < 4; ++nt)
#pragma unroll
            for (int r = 0; r < 4; ++r)
                s_acc[nt][r] -= 1e9f * Mrow[(size_t)r * T_SEQ + kv0 + nt * 16 + col];

        // online softmax per C/D row (16-lane quad reduction)
#pragma unroll
        for (int r = 0; r < 4; ++r) {
            float mx = fmaxf(fmaxf(s_acc[0][r], s_acc[1][r]), fmaxf(s_acc[2][r], s_acc[3][r]));
#pragma unroll
            for (int off = 1; off < 16; off <<= 1) mx = fmaxf(mx, __shfl_xor(mx, off));
            float mnew = fmaxf(m_run[r], mx);
            float alpha = __expf(m_run[r] - mnew);
            m_run[r] = mnew;
            float rs = 0.f;
#pragma unroll
            for (int nt = 0; nt < 4; ++nt) {
                float p = __expf(s_acc[nt][r] - mnew);
                rs += p;
                Ps[wave * 16 + quad * 4 + r][nt * 16 + col] = f2bf(p);
            }
#pragma unroll
            for (int off = 1; off < 16; off <<= 1) rs += __shfl_xor(rs, off);
            l_run[r] = l_run[r] * alpha + rs;
#pragma unroll
            for (int st = 0; st < 4; ++st) o_acc[st][r] *= alpha;
        }
        // PV: this wave reads only the Ps rows it wrote (no barrier needed)
        bf16x8 pa0 = *(const bf16x8*)&Ps[wave * 16 + col][quad * 8];
        bf16x8 pa1 = *(const bf16x8*)&Ps[wave * 16 + col][32 + quad * 8];
#pragma unroll
        for (int st = 0; st < 4; ++st) {
            bf16x8 vb0 = *(const bf16x8*)&Vs[st * 16 + col][quad * 8];
            bf16x8 vb1 = *(const bf16x8*)&Vs[st * 16 + col][32 + quad * 8];
            o_acc[st] = __builtin_amdgcn_mfma_f32_16x16x32_bf16(pa0, vb0, o_acc[st], 0, 0, 0);
            o_acc[st] = __builtin_amdgcn_mfma_f32_16x16x32_bf16(pa1, vb1, o_acc[st], 0, 0, 0);
        }
        __syncthreads();
    }

#pragma unroll
    for (int r = 0; r < 4; ++r) {
        float inv = 1.0f / l_run[r];
        int qrow = q0 + wave * 16 + quad * 4 + r;
        size_t base = (size_t)(n * T_SEQ + qrow) * ldo + h * 64;
#pragma unroll
        for (int st = 0; st < 4; ++st)
            O[base + st * 16 + col] = f2bf(o_acc[st][r] * inv);
    }
}

extern "C" void kernel_launch(void* const* d_in, const int* in_sizes, int n_in,
                              void* d_out, int out_size, void* d_ws, size_t ws_size,
                              hipStream_t stream) {
    const float* q_seqs = (const float*)d_in[0];
    const float* r_seqs = (const float*)d_in[1];
    const float* mask   = (const float*)d_in[2];
    const float* Wq     = (const float*)d_in[3];
    const float* Wk     = (const float*)d_in[4];
    const float* Wv     = (const float*)d_in[5];
    const float* Wo     = (const float*)d_in[6];

    const size_t R = 4194304;  // region stride in ushorts (8 MiB)
    ushort_t* ws = (ushort_t*)d_ws;
    ushort_t* bfQ  = ws;            // R0: q_seqs bf16; later reused as wsO
    ushort_t* bfR  = ws + R;        // R1: r_seqs bf16; later reused as wsVT
    ushort_t* WqT  = ws + 2 * R;    // R2: WqT | WkvT (2048 rows) | WoT
    ushort_t* WkvT = WqT + 1048576;
    ushort_t* WoT  = WqT + 3145728;
    ushort_t* wsQ  = ws + 3 * R;    // R3
    ushort_t* wsKV = ws + 4 * R;    // R4+R5: [4096][2048]
    ushort_t* wsVT = bfR;
    ushort_t* wsO  = bfQ;

    dim3 blk(256);

    hipLaunchKernelGGL(cvt_bf16, dim3(2048), blk, 0, stream, q_seqs, bfQ);
    hipLaunchKernelGGL(cvt_bf16, dim3(2048), blk, 0, stream, r_seqs, bfR);
    hipLaunchKernelGGL(cvt_w_t, dim3(16, 16), blk, 0, stream, Wq, WqT);
    hipLaunchKernelGGL(cvt_w_t, dim3(16, 16), blk, 0, stream, Wk, WkvT);
    hipLaunchKernelGGL(cvt_w_t, dim3(16, 16), blk, 0, stream, Wv, WkvT + 1024 * 1024);
    hipLaunchKernelGGL(cvt_w_t, dim3(16, 16), blk, 0, stream, Wo, WoT);

    // Q projection (scaled) and fused K|V projection
    hipLaunchKernelGGL(gemm_mfma128, dim3(8, 32), blk, 0, stream,
                       bfQ, WqT, (void*)wsQ, 4096, 1024, 1024, 0.125f, 0);
    hipLaunchKernelGGL(gemm_mfma128, dim3(16, 32), blk, 0, stream,
                       bfR, WkvT, (void*)wsKV, 4096, 2048, 1024, 1.0f, 0);

    // transpose V (cols 1024..2047 of wsKV) -> [b,h,s,t]
    hipLaunchKernelGGL(transpose_v, dim3(32, 16, 2), blk, 0, stream,
                       wsKV + 1024, 2048, wsVT);

    hipLaunchKernelGGL(attn_mfma, dim3(32, 16, 2), blk, 0, stream,
                       wsQ, 1024, wsKV, 2048, wsVT, mask, wsO, 1024);

    hipLaunchKernelGGL(gemm_mfma128, dim3(8, 32), blk, 0, stream,
                       wsO, WoT, d_out, 4096, 1024, 1024, 1.0f, 1);
}

// Round 6
// 938.363 us; speedup vs baseline: 10.4099x; 1.0512x over previous
//
#include <hip/hip_runtime.h>

typedef unsigned short ushort_t;
typedef __attribute__((ext_vector_type(8))) short bf16x8;   // 8 bf16 = 4 VGPRs
typedef __attribute__((ext_vector_type(4))) float f32x4;

#define T_SEQ 2048

__device__ __forceinline__ ushort_t f2bf(float f) {
    unsigned u = __float_as_uint(f);
    unsigned r = u + 0x7FFFu + ((u >> 16) & 1u);
    return (ushort_t)(r >> 16);
}
__device__ __forceinline__ unsigned pack2(float a, float b) {
    return (unsigned)f2bf(a) | ((unsigned)f2bf(b) << 16);
}

// ---- fp32 -> bf16, same layout. ----
__global__ __launch_bounds__(256) void cvt_bf16(const float* __restrict__ in,
                                                ushort_t* __restrict__ out) {
    size_t i = ((size_t)blockIdx.x * 256 + threadIdx.x) * 8;
    float4 f0 = *(const float4*)(in + i);
    float4 f1 = *(const float4*)(in + i + 4);
    uint4 w;
    w.x = pack2(f0.x, f0.y); w.y = pack2(f0.z, f0.w);
    w.z = pack2(f1.x, f1.y); w.w = pack2(f1.z, f1.w);
    *(uint4*)(out + i) = w;
}

// ---- weight fp32 [1024][1024] ([k][n]) -> bf16 transposed out[n][k] ----
__global__ __launch_bounds__(256) void cvt_w_t(const float* __restrict__ W,
                                               ushort_t* __restrict__ out) {
    __shared__ ushort_t Ls[64][72];
    const int t = threadIdx.x;
    const int k0 = blockIdx.y * 64, n0 = blockIdx.x * 64;
    {
        const int r = t >> 2, c = (t & 3) * 16;
        const float* p = W + (size_t)(k0 + r) * 1024 + n0 + c;
        float4 a = *(const float4*)p, b = *(const float4*)(p + 4);
        float4 c2 = *(const float4*)(p + 8), d = *(const float4*)(p + 12);
        uint4 w0, w1;
        w0.x = pack2(a.x, a.y); w0.y = pack2(a.z, a.w);
        w0.z = pack2(b.x, b.y); w0.w = pack2(b.z, b.w);
        w1.x = pack2(c2.x, c2.y); w1.y = pack2(c2.z, c2.w);
        w1.z = pack2(d.x, d.y); w1.w = pack2(d.z, d.w);
        *(uint4*)&Ls[r][c] = w0;
        *(uint4*)&Ls[r][c + 8] = w1;
    }
    __syncthreads();
    {
        const int nn = t >> 2, kc = (t & 3) * 16;
        unsigned u[8];
#pragma unroll
        for (int a2 = 0; a2 < 8; ++a2)
            u[a2] = (unsigned)Ls[kc + 2 * a2][nn] | ((unsigned)Ls[kc + 2 * a2 + 1][nn] << 16);
        uint4 w0 = {u[0], u[1], u[2], u[3]}, w1 = {u[4], u[5], u[6], u[7]};
        ushort_t* op = out + (size_t)(n0 + nn) * 1024 + k0 + kc;
        *(uint4*)op = w0;
        *(uint4*)(op + 8) = w1;
    }
}

// ---- V bf16 [b*2048+t][ldin] -> VT [((b*16+h)*64+s)][2048] ----
__global__ __launch_bounds__(256) void transpose_v(const ushort_t* __restrict__ Vin, int ldin,
                                                   ushort_t* __restrict__ VT) {
    __shared__ ushort_t Ls[64][72];
    const int t = threadIdx.x;
    const int t0 = blockIdx.x * 64;
    const int h = blockIdx.y, b = blockIdx.z;
    {
        const int r = t >> 2, c = (t & 3) * 16;
        const ushort_t* p = Vin + (size_t)(b * T_SEQ + t0 + r) * ldin + h * 64 + c;
        *(uint4*)&Ls[r][c] = *(const uint4*)p;
        *(uint4*)&Ls[r][c + 8] = *(const uint4*)(p + 8);
    }
    __syncthreads();
    {
        const int s = t >> 2, tc = (t & 3) * 16;
        unsigned u[8];
#pragma unroll
        for (int a2 = 0; a2 < 8; ++a2)
            u[a2] = (unsigned)Ls[tc + 2 * a2][s] | ((unsigned)Ls[tc + 2 * a2 + 1][s] << 16);
        uint4 w0 = {u[0], u[1], u[2], u[3]}, w1 = {u[4], u[5], u[6], u[7]};
        ushort_t* op = VT + ((size_t)(b * 16 + h) * 64 + s) * T_SEQ + t0 + tc;
        *(uint4*)op = w0;
        *(uint4*)(op + 8) = w1;
    }
}

// ---- GEMM: C[M,N] = scale * A[M,K] * Bt[N,K]^T, bf16 in, fp32 acc.
// 128x128 tile, BK=64, plain vector staging (no global_load_lds). ----
__global__ __launch_bounds__(256) void gemm128(
    const ushort_t* __restrict__ A, const ushort_t* __restrict__ Bt,
    void* __restrict__ Cv, int M, int N, int K, float scale, int cF32)
{
    __shared__ ushort_t As[128][64];
    __shared__ ushort_t Bs[128][64];
    const int t = threadIdx.x;
    const int lane = t & 63, wave = t >> 6;
    const int col = lane & 15, quad = lane >> 4;
    const int wm = wave & 1, wn = wave >> 1;
    const int m0 = blockIdx.y * 128, n0 = blockIdx.x * 128;

    f32x4 acc[4][4];
#pragma unroll
    for (int i = 0; i < 4; ++i)
#pragma unroll
        for (int j = 0; j < 4; ++j) acc[i][j] = (f32x4){0.f, 0.f, 0.f, 0.f};

    for (int k0 = 0; k0 < K; k0 += 64) {
#pragma unroll
        for (int j = 0; j < 4; ++j) {
            const int c = j * 256 + t;
            const int row = c >> 3, cc = (c & 7) * 8;
            *(uint4*)&As[row][cc] = *(const uint4*)(A + (size_t)(m0 + row) * K + k0 + cc);
            *(uint4*)&Bs[row][cc] = *(const uint4*)(Bt + (size_t)(n0 + row) * K + k0 + cc);
        }
        __syncthreads();
#pragma unroll
        for (int kk = 0; kk < 2; ++kk) {
            bf16x8 a[4], b[4];
#pragma unroll
            for (int i = 0; i < 4; ++i)
                a[i] = *(const bf16x8*)&As[wm * 64 + i * 16 + col][kk * 32 + quad * 8];
#pragma unroll
            for (int j = 0; j < 4; ++j)
                b[j] = *(const bf16x8*)&Bs[wn * 64 + j * 16 + col][kk * 32 + quad * 8];
#pragma unroll
            for (int i = 0; i < 4; ++i)
#pragma unroll
                for (int j = 0; j < 4; ++j)
                    acc[i][j] = __builtin_amdgcn_mfma_f32_16x16x32_bf16(a[i], b[j], acc[i][j], 0, 0, 0);
        }
        __syncthreads();
    }
#pragma unroll
    for (int i = 0; i < 4; ++i) {
        const int row = m0 + wm * 64 + i * 16 + quad * 4;
#pragma unroll
        for (int j = 0; j < 4; ++j) {
            const int cc = n0 + wn * 64 + j * 16 + col;
#pragma unroll
            for (int r = 0; r < 4; ++r) {
                float v = acc[i][j][r] * scale;
                if (cF32) ((float*)Cv)[(size_t)(row + r) * N + cc] = v;
                else      ((ushort_t*)Cv)[(size_t)(row + r) * N + cc] = f2bf(v);
            }
        }
    }
}

// ---- flash attention, KV-tile = 128 (16 iterations). Q-tile 64.
// Q,K rows strided (bf16); VT pre-transposed [b,h,s][t]; Mask fp32. ----
__global__ __launch_bounds__(256) void attn_kv128(
    const ushort_t* __restrict__ Q, int ldq,
    const ushort_t* __restrict__ K, int ldk,
    const ushort_t* __restrict__ VT,
    const float* __restrict__ Mask,
    ushort_t* __restrict__ O, int ldo)
{
    __shared__ ushort_t Qs[64][72];
    __shared__ ushort_t Ks[128][72];   // [kv][s]
    __shared__ ushort_t Vs[64][136];   // [s][kv]  (from VT)
    __shared__ ushort_t Ps[64][72];    // [q][kv-local 64]

    const int t = threadIdx.x;
    const int lane = t & 63, wave = t >> 6;
    const int col = lane & 15, quad = lane >> 4;
    const int q0 = blockIdx.x * 64;
    const int h = blockIdx.y, n = blockIdx.z;

    {   // stage Q once
        const int r = t >> 2, c = (t & 3) * 16;
        const ushort_t* p = Q + (size_t)(n * T_SEQ + q0 + r) * ldq + h * 64 + c;
        *(uint4*)&Qs[r][c]     = *(const uint4*)p;
        *(uint4*)&Qs[r][c + 8] = *(const uint4*)(p + 8);
    }
    __syncthreads();
    const bf16x8 qa0 = *(const bf16x8*)&Qs[wave * 16 + col][quad * 8];
    const bf16x8 qa1 = *(const bf16x8*)&Qs[wave * 16 + col][32 + quad * 8];

    f32x4 o_acc[4];
#pragma unroll
    for (int i = 0; i < 4; ++i) o_acc[i] = (f32x4){0.f, 0.f, 0.f, 0.f};
    float m_run[4], l_run[4];
#pragma unroll
    for (int r = 0; r < 4; ++r) { m_run[r] = -3e38f; l_run[r] = 0.f; }

    const float* Mrow = Mask + ((size_t)((n * 16 + h) * T_SEQ) + q0 + wave * 16 + quad * 4) * T_SEQ;

    for (int kt = 0; kt < T_SEQ / 128; ++kt) {
        const int kv0 = kt * 128;

        // mask prefetch (independent of staging; overlaps its latency + barrier)
        float mk[8][4];
#pragma unroll
        for (int nt = 0; nt < 8; ++nt)
#pragma unroll
            for (int r = 0; r < 4; ++r)
                mk[nt][r] = Mrow[(size_t)r * T_SEQ + kv0 + nt * 16 + col];

        {   // stage K tile: 128 rows x 64 cols
            const int r = t >> 2, c = (t & 3) * 16;
#pragma unroll
            for (int p64 = 0; p64 < 128; p64 += 64) {
                const ushort_t* p = K + (size_t)(n * T_SEQ + kv0 + p64 + r) * ldk + h * 64 + c;
                *(uint4*)&Ks[p64 + r][c]     = *(const uint4*)p;
                *(uint4*)&Ks[p64 + r][c + 8] = *(const uint4*)(p + 8);
            }
        }
        {   // stage V^T tile: 64 s-rows x 128 kv-cols
            const int s = t >> 2, cb = (t & 3) * 32;
            const ushort_t* p = VT + ((size_t)(n * 16 + h) * 64 + s) * T_SEQ + kv0 + cb;
            *(uint4*)&Vs[s][cb]      = *(const uint4*)p;
            *(uint4*)&Vs[s][cb + 8]  = *(const uint4*)(p + 8);
            *(uint4*)&Vs[s][cb + 16] = *(const uint4*)(p + 16);
            *(uint4*)&Vs[s][cb + 24] = *(const uint4*)(p + 24);
        }
        __syncthreads();

        // S = Q.K^T over 128 kv cols (8 chunks of 16)
        f32x4 s_acc[8];
#pragma unroll
        for (int nt = 0; nt < 8; ++nt) {
            bf16x8 kb0 = *(const bf16x8*)&Ks[nt * 16 + col][quad * 8];
            bf16x8 kb1 = *(const bf16x8*)&Ks[nt * 16 + col][32 + quad * 8];
            f32x4 z = (f32x4){0.f, 0.f, 0.f, 0.f};
            z = __builtin_amdgcn_mfma_f32_16x16x32_bf16(qa0, kb0, z, 0, 0, 0);
            z = __builtin_amdgcn_mfma_f32_16x16x32_bf16(qa1, kb1, z, 0, 0, 0);
            s_acc[nt] = z;
#pragma unroll
            for (int r = 0; r < 4; ++r) s_acc[nt][r] -= 1e9f * mk[nt][r];
        }

        // online softmax across 128 cols; exp stored back into s_acc
#pragma unroll
        for (int r = 0; r < 4; ++r) {
            float mx = s_acc[0][r];
#pragma unroll
            for (int nt = 1; nt < 8; ++nt) mx = fmaxf(mx, s_acc[nt][r]);
#pragma unroll
            for (int off = 1; off < 16; off <<= 1) mx = fmaxf(mx, __shfl_xor(mx, off));
            float mnew = fmaxf(m_run[r], mx);
            float alpha = __expf(m_run[r] - mnew);
            m_run[r] = mnew;
            float rs = 0.f;
#pragma unroll
            for (int nt = 0; nt < 8; ++nt) {
                float p = __expf(s_acc[nt][r] - mnew);
                s_acc[nt][r] = p;
                rs += p;
            }
#pragma unroll
            for (int off = 1; off < 16; off <<= 1) rs += __shfl_xor(rs, off);
            l_run[r] = l_run[r] * alpha + rs;
#pragma unroll
            for (int st = 0; st < 4; ++st) o_acc[st][r] *= alpha;
        }

        // PV in two 64-col chunks; Ps rows are wave-private -> no barrier
#pragma unroll
        for (int ch = 0; ch < 2; ++ch) {
#pragma unroll
            for (int nt = 0; nt < 4; ++nt)
#pragma unroll
                for (int r = 0; r < 4; ++r)
                    Ps[wave * 16 + quad * 4 + r][nt * 16 + col] = f2bf(s_acc[ch * 4 + nt][r]);
            bf16x8 pa0 = *(const bf16x8*)&Ps[wave * 16 + col][quad * 8];
            bf16x8 pa1 = *(const bf16x8*)&Ps[wave * 16 + col][32 + quad * 8];
#pragma unroll
            for (int st = 0; st < 4; ++st) {
                bf16x8 vb0 = *(const bf16x8*)&Vs[st * 16 + col][ch * 64 + quad * 8];
                bf16x8 vb1 = *(const bf16x8*)&Vs[st * 16 + col][ch * 64 + 32 + quad * 8];
                o_acc[st] = __builtin_amdgcn_mfma_f32_16x16x32_bf16(pa0, vb0, o_acc[st], 0, 0, 0);
                o_acc[st] = __builtin_amdgcn_mfma_f32_16x16x32_bf16(pa1, vb1, o_acc[st], 0, 0, 0);
            }
        }
        __syncthreads();
    }

#pragma unroll
    for (int r = 0; r < 4; ++r) {
        float inv = 1.0f / l_run[r];
        int qrow = q0 + wave * 16 + quad * 4 + r;
        size_t base = (size_t)(n * T_SEQ + qrow) * ldo + h * 64;
#pragma unroll
        for (int st = 0; st < 4; ++st)
            O[base + st * 16 + col] = f2bf(o_acc[st][r] * inv);
    }
}

extern "C" void kernel_launch(void* const* d_in, const int* in_sizes, int n_in,
                              void* d_out, int out_size, void* d_ws, size_t ws_size,
                              hipStream_t stream) {
    const float* q_seqs = (const float*)d_in[0];
    const float* r_seqs = (const float*)d_in[1];
    const float* mask   = (const float*)d_in[2];
    const float* Wq     = (const float*)d_in[3];
    const float* Wk     = (const float*)d_in[4];
    const float* Wv     = (const float*)d_in[5];
    const float* Wo     = (const float*)d_in[6];

    const size_t R = 4194304;  // region stride in ushorts (8 MiB)
    ushort_t* ws = (ushort_t*)d_ws;
    ushort_t* bfQ  = ws;            // R0: q_seqs bf16; later reused as wsO
    ushort_t* bfR  = ws + R;        // R1: r_seqs bf16; later reused as wsVT
    ushort_t* WqT  = ws + 2 * R;    // R2: WqT | WkvT (2048 rows) | WoT
    ushort_t* WkvT = WqT + 1048576;
    ushort_t* WoT  = WqT + 3145728;
    ushort_t* wsQ  = ws + 3 * R;    // R3
    ushort_t* wsKV = ws + 4 * R;    // R4+R5: [4096][2048]
    ushort_t* wsVT = bfR;
    ushort_t* wsO  = bfQ;

    dim3 blk(256);

    hipLaunchKernelGGL(cvt_bf16, dim3(2048), blk, 0, stream, q_seqs, bfQ);
    hipLaunchKernelGGL(cvt_bf16, dim3(2048), blk, 0, stream, r_seqs, bfR);
    hipLaunchKernelGGL(cvt_w_t, dim3(16, 16), blk, 0, stream, Wq, WqT);
    hipLaunchKernelGGL(cvt_w_t, dim3(16, 16), blk, 0, stream, Wk, WkvT);
    hipLaunchKernelGGL(cvt_w_t, dim3(16, 16), blk, 0, stream, Wv, WkvT + 1024 * 1024);
    hipLaunchKernelGGL(cvt_w_t, dim3(16, 16), blk, 0, stream, Wo, WoT);

    hipLaunchKernelGGL(gemm128, dim3(8, 32), blk, 0, stream,
                       bfQ, WqT, (void*)wsQ, 4096, 1024, 1024, 0.125f, 0);
    hipLaunchKernelGGL(gemm128, dim3(16, 32), blk, 0, stream,
                       bfR, WkvT, (void*)wsKV, 4096, 2048, 1024, 1.0f, 0);

    hipLaunchKernelGGL(transpose_v, dim3(32, 16, 2), blk, 0, stream,
                       wsKV + 1024, 2048, wsVT);

    hipLaunchKernelGGL(attn_kv128, dim3(32, 16, 2), blk, 0, stream,
                       wsQ, 1024, wsKV, 2048, wsVT, mask, wsO, 1024);

    hipLaunchKernelGGL(gemm128, dim3(8, 32), blk, 0, stream,
                       wsO, WoT, d_out, 4096, 1024, 1024, 1.0f, 1);
}